// Round 1
// baseline (80.024 us; speedup 1.0000x reference)
//
#include <hip/hip_runtime.h>

#define B_SZ 256
#define D_SZ 256
#define N_TOT 512   // 2*B

// ws layout (doubles): ws[0] = weighted l2_cum total (for bandwidth), ws[1] = loss accumulator

// ---------------------------------------------------------------------------
// Kernel 1: per-column S1/S2 over all 512 rows, then weighted closed-form sum:
//   sum(l2_cum) = sum_d (D-d) * (2*n*S2[d] - 2*S1[d]^2)
// 8 blocks x 256 threads; block b handles columns [32b, 32b+32), 8 row-groups.
// ---------------------------------------------------------------------------
__global__ __launch_bounds__(256) void bw_kernel(const float* __restrict__ src,
                                                 const float* __restrict__ tgt,
                                                 double* __restrict__ ws) {
    const int tx   = threadIdx.x;
    const int col  = (blockIdx.x << 5) + (tx & 31);   // 0..255
    const int rgrp = tx >> 5;                         // 0..7

    double s1 = 0.0, s2 = 0.0;
    for (int r = rgrp; r < N_TOT; r += 8) {
        const float* row = (r < B_SZ) ? (src + r * D_SZ) : (tgt + (r - B_SZ) * D_SZ);
        float v = row[col];
        s1 += (double)v;
        s2 += (double)v * (double)v;
    }

    __shared__ double sh1[8][32];
    __shared__ double sh2[8][32];
    sh1[rgrp][tx & 31] = s1;
    sh2[rgrp][tx & 31] = s2;
    __syncthreads();

    if (tx < 32) {
        double S1 = 0.0, S2 = 0.0;
        #pragma unroll
        for (int g = 0; g < 8; ++g) { S1 += sh1[g][tx]; S2 += sh2[g][tx]; }
        int c = (blockIdx.x << 5) + tx;
        double pairsum = 2.0 * (double)N_TOT * S2 - 2.0 * S1 * S1;
        double local   = (double)(D_SZ - c) * pairsum;
        // reduce 32 lanes (lane0 dependency tree stays within lanes 0..31)
        #pragma unroll
        for (int off = 16; off > 0; off >>= 1)
            local += __shfl_down(local, off, 64);
        if (tx == 0) atomicAdd(&ws[0], local);
    }
}

// ---------------------------------------------------------------------------
// Kernel 2: 1024 pairs (256 i-indices x 4 pair types), one wave per pair.
// Lane l handles dims [4l, 4l+4): float4 loads, local prefix, wave scan,
// 5 bandwidths x 4 dims expf, signed double accumulation.
// ---------------------------------------------------------------------------
__global__ __launch_bounds__(256) void loss_kernel(const float* __restrict__ src,
                                                   const float* __restrict__ tgt,
                                                   double* __restrict__ ws) {
    const int tx       = threadIdx.x;
    const int lane     = tx & 63;
    const int waveBlk  = tx >> 6;                  // 0..3
    const int wid      = blockIdx.x * 4 + waveBlk; // 0..1023
    const int p        = wid & 255;                // i
    const int t        = wid >> 8;                 // pair type
    const int q        = (p + 1) & 255;            // j = (i+1)%B

    const float* rowA;
    const float* rowB;
    double sign;
    if (t == 0)      { rowA = src + p * D_SZ; rowB = src + q * D_SZ; sign =  1.0; }  // (i, j)
    else if (t == 1) { rowA = tgt + p * D_SZ; rowB = tgt + q * D_SZ; sign =  1.0; }  // (i+b, j+b)
    else if (t == 2) { rowA = src + p * D_SZ; rowB = tgt + q * D_SZ; sign = -1.0; }  // (i, j+b)
    else             { rowA = src + q * D_SZ; rowB = tgt + p * D_SZ; sign = -1.0; }  // (j, i+b)

    // bandwidth from kernel-1 total
    double total = ws[0];
    float  bw    = (float)(total / ((double)N_TOT * (double)(N_TOT - 1)) * 0.25);

    float4 a = ((const float4*)rowA)[lane];
    float4 b = ((const float4*)rowB)[lane];
    float d0 = a.x - b.x, d1 = a.y - b.y, d2 = a.z - b.z, d3 = a.w - b.w;
    float c0 = d0 * d0;
    float c1 = c0 + d1 * d1;
    float c2 = c1 + d2 * d2;
    float c3 = c2 + d3 * d3;

    // inclusive wave scan of per-lane totals
    float s = c3;
    #pragma unroll
    for (int off = 1; off < 64; off <<= 1) {
        float v = __shfl_up(s, off, 64);
        if (lane >= off) s += v;
    }
    float prefix = __shfl_up(s, 1, 64);
    if (lane == 0) prefix = 0.f;

    float cum0 = prefix + c0;
    float cum1 = prefix + c1;
    float cum2 = prefix + c2;
    float cum3 = prefix + c3;

    float acc = 0.f;
    float inv = 1.0f / bw;
    #pragma unroll
    for (int k = 0; k < 5; ++k) {
        acc += expf(-cum0 * inv) + expf(-cum1 * inv) + expf(-cum2 * inv) + expf(-cum3 * inv);
        inv *= 0.5f;
    }

    double lacc = (double)acc * sign;
    #pragma unroll
    for (int off = 32; off > 0; off >>= 1)
        lacc += __shfl_down(lacc, off, 64);

    __shared__ double blk[4];
    if (lane == 0) blk[waveBlk] = lacc;
    __syncthreads();
    if (tx == 0) {
        double v = blk[0] + blk[1] + blk[2] + blk[3];
        atomicAdd(&ws[1], v);
    }
}

// ---------------------------------------------------------------------------
// Kernel 3: finalize  out = loss_sum / (B * D)
// ---------------------------------------------------------------------------
__global__ void final_kernel(const double* __restrict__ ws, float* __restrict__ out) {
    out[0] = (float)(ws[1] * (1.0 / ((double)B_SZ * (double)D_SZ)));
}

extern "C" void kernel_launch(void* const* d_in, const int* in_sizes, int n_in,
                              void* d_out, int out_size, void* d_ws, size_t ws_size,
                              hipStream_t stream) {
    const float* src = (const float*)d_in[0];
    const float* tgt = (const float*)d_in[1];
    float* out = (float*)d_out;
    double* ws = (double*)d_ws;

    hipMemsetAsync(ws, 0, 2 * sizeof(double), stream);
    bw_kernel<<<8, 256, 0, stream>>>(src, tgt, ws);
    loss_kernel<<<256, 256, 0, stream>>>(src, tgt, ws);
    final_kernel<<<1, 1, 0, stream>>>(ws, out);
}

// Round 2
// 70.941 us; speedup vs baseline: 1.1280x; 1.1280x over previous
//
#include <hip/hip_runtime.h>

#define B_SZ 256
#define D_SZ 256
#define N_TOT 512   // 2*B

// ws layout (doubles): ws[0..255] = per-block signed loss partials

// ---------------------------------------------------------------------------
// Fused kernel: 256 blocks x 256 threads.
// Phase A (redundant per block): column sums S1/S2 over all 512 rows ->
//   sum(l2_cum) = sum_d (D-d) * (2*n*S2[d] - 2*S1[d]^2)  -> bandwidth.
//   Input is 512 KB, L2-resident after first touch; redundancy is ~free.
// Phase B: each of the 4 waves handles one of this block's 4 pairs
//   (wid = blockIdx*4 + wave; p = wid&255, type = wid>>8).
//   Lane l covers dims [4l,4l+4): float4 loads, wave inclusive scan for the
//   feature-axis cumsum, 5-bandwidth Gaussian sum, signed double reduce.
// Block partial -> ws[blockIdx] (fully overwritten every call; no memset).
// ---------------------------------------------------------------------------
__global__ __launch_bounds__(256) void fused_kernel(const float* __restrict__ src,
                                                    const float* __restrict__ tgt,
                                                    double* __restrict__ partial) {
    const int tx = threadIdx.x;

    // ---- Phase A: this thread owns column tx ----
    double s1 = 0.0, s2 = 0.0;
    #pragma unroll 8
    for (int r = 0; r < B_SZ; ++r) {
        float a = src[r * D_SZ + tx];
        float b = tgt[r * D_SZ + tx];
        s1 += (double)a + (double)b;
        s2 += (double)a * (double)a + (double)b * (double)b;
    }
    double pairsum = 2.0 * (double)N_TOT * s2 - 2.0 * s1 * s1;
    double local   = (double)(D_SZ - tx) * pairsum;

    // block-reduce 256 doubles -> total
    const int lane    = tx & 63;
    const int waveBlk = tx >> 6;
    #pragma unroll
    for (int off = 32; off > 0; off >>= 1)
        local += __shfl_down(local, off, 64);

    __shared__ double shred[4];
    __shared__ double sh_bw;
    if (lane == 0) shred[waveBlk] = local;
    __syncthreads();
    if (tx == 0) {
        double total = shred[0] + shred[1] + shred[2] + shred[3];
        // bandwidth = total/(n^2-n) / (kernel_mul^(num/2)) = total/(n^2-n)/4
        sh_bw = total / ((double)N_TOT * (double)(N_TOT - 1)) * 0.25;
    }
    __syncthreads();
    const float bw = (float)sh_bw;

    // ---- Phase B: wave -> pair ----
    const int wid = blockIdx.x * 4 + waveBlk;   // 0..1023
    const int p   = wid & 255;
    const int t   = wid >> 8;
    const int q   = (p + 1) & 255;

    const float* rowA;
    const float* rowB;
    double sign;
    if (t == 0)      { rowA = src + p * D_SZ; rowB = src + q * D_SZ; sign =  1.0; }
    else if (t == 1) { rowA = tgt + p * D_SZ; rowB = tgt + q * D_SZ; sign =  1.0; }
    else if (t == 2) { rowA = src + p * D_SZ; rowB = tgt + q * D_SZ; sign = -1.0; }
    else             { rowA = src + q * D_SZ; rowB = tgt + p * D_SZ; sign = -1.0; }

    float4 a4 = ((const float4*)rowA)[lane];
    float4 b4 = ((const float4*)rowB)[lane];
    float d0 = a4.x - b4.x, d1 = a4.y - b4.y, d2 = a4.z - b4.z, d3 = a4.w - b4.w;
    float c0 = d0 * d0;
    float c1 = c0 + d1 * d1;
    float c2 = c1 + d2 * d2;
    float c3 = c2 + d3 * d3;

    // inclusive wave scan of per-lane totals
    float s = c3;
    #pragma unroll
    for (int off = 1; off < 64; off <<= 1) {
        float v = __shfl_up(s, off, 64);
        if (lane >= off) s += v;
    }
    float prefix = __shfl_up(s, 1, 64);
    if (lane == 0) prefix = 0.f;

    float cum0 = prefix + c0;
    float cum1 = prefix + c1;
    float cum2 = prefix + c2;
    float cum3 = prefix + c3;

    float acc = 0.f;
    float inv = 1.0f / bw;
    #pragma unroll
    for (int k = 0; k < 5; ++k) {
        acc += expf(-cum0 * inv) + expf(-cum1 * inv) + expf(-cum2 * inv) + expf(-cum3 * inv);
        inv *= 0.5f;
    }

    double lacc = (double)acc * sign;
    #pragma unroll
    for (int off = 32; off > 0; off >>= 1)
        lacc += __shfl_down(lacc, off, 64);

    __shared__ double blk[4];
    if (lane == 0) blk[waveBlk] = lacc;
    __syncthreads();
    if (tx == 0)
        partial[blockIdx.x] = blk[0] + blk[1] + blk[2] + blk[3];
}

// ---------------------------------------------------------------------------
// Final: reduce 256 block partials, out = sum / (B*D)
// ---------------------------------------------------------------------------
__global__ __launch_bounds__(256) void final_kernel(const double* __restrict__ partial,
                                                    float* __restrict__ out) {
    const int tx   = threadIdx.x;
    const int lane = tx & 63;
    const int wv   = tx >> 6;

    double v = partial[tx];
    #pragma unroll
    for (int off = 32; off > 0; off >>= 1)
        v += __shfl_down(v, off, 64);

    __shared__ double sh[4];
    if (lane == 0) sh[wv] = v;
    __syncthreads();
    if (tx == 0)
        out[0] = (float)((sh[0] + sh[1] + sh[2] + sh[3]) *
                         (1.0 / ((double)B_SZ * (double)D_SZ)));
}

extern "C" void kernel_launch(void* const* d_in, const int* in_sizes, int n_in,
                              void* d_out, int out_size, void* d_ws, size_t ws_size,
                              hipStream_t stream) {
    const float* src = (const float*)d_in[0];
    const float* tgt = (const float*)d_in[1];
    float* out = (float*)d_out;
    double* ws = (double*)d_ws;

    fused_kernel<<<256, 256, 0, stream>>>(src, tgt, ws);
    final_kernel<<<1, 256, 0, stream>>>(ws, out);
}